// Round 1
// baseline (8797.590 us; speedup 1.0000x reference)
//
#include <hip/hip_runtime.h>
#include <hip/hip_bf16.h>

// Problem constants (match reference)
#define NN 100000     // nodes
#define NE 1600000    // edges
#define HD 128        // feature/hidden dim
#define NG 512        // graphs
#define BN_EPS 1e-5f

__device__ __forceinline__ void atomAddF(float* p, float v) {
    unsafeAtomicAdd(p, v);   // global_atomic_add_f32 on gfx950
}

// ---------------- degree / norm ----------------
__global__ void k_deg_init(float* deg) {
    int i = blockIdx.x * 256 + threadIdx.x;
    if (i < NN) deg[i] = 1.0f;   // self-loop contribution
}

__global__ void k_deg_accum(const int* __restrict__ dst, float* deg) {
    int e = blockIdx.x * 256 + threadIdx.x;
    if (e < NE) atomAddF(&deg[dst[e]], 1.0f);
}

__global__ void k_dinv(float* deg) {
    int i = blockIdx.x * 256 + threadIdx.x;
    if (i < NN) deg[i] = rsqrtf(fmaxf(deg[i], 1.0f));
}

// ---------------- BN affine prep ----------------
// scale = g * rsqrt(v+eps); shift = (b - m)*scale + be   (conv bias b folded in)
__global__ void k_bn_prep(const float* __restrict__ b, const float* __restrict__ g,
                          const float* __restrict__ be, const float* __restrict__ m,
                          const float* __restrict__ v, float* scale, float* shift) {
    int f = threadIdx.x;
    if (f < HD) {
        float sc = g[f] * rsqrtf(v[f] + BN_EPS);
        scale[f] = sc;
        shift[f] = (b[f] - m[f]) * sc + be[f];
    }
}

// ---------------- GEMM: h = x @ W, epilogue hs = h*dinv, agg = hs*dinv ----------------
// 32 rows per block, 256 threads, k-slabbed (32) through LDS.
// NOTE: writes agg in-place over xin rows are safe: each block's global reads of
// its rows complete (staged via LDS) before the epilogue writes.
#define GROWS 32
__launch_bounds__(256)
__global__ void k_gemm(const float* __restrict__ xin, const float* __restrict__ W,
                       const float* __restrict__ dinv,
                       float* __restrict__ hs, float* __restrict__ agg) {
    __shared__ float sW[32 * 128];      // k-slab of W: [32 k][128 c]
    __shared__ float sX[32 * 36];       // x tile: [32 rows][32 k], stride 36 (bank-spread)
    const int tid = threadIdx.x;
    const long row0 = (long)blockIdx.x * GROWS;

    const int cg = tid & 15;            // 16 column groups x 8 cols
    const int rp = tid >> 4;            // 16 row pairs x 2 rows
    const int c0 = cg * 8;
    const int r0 = rp * 2;

    float acc0[8], acc1[8];
#pragma unroll
    for (int j = 0; j < 8; ++j) { acc0[j] = 0.f; acc1[j] = 0.f; }

    for (int ks = 0; ks < 128; ks += 32) {
        // load W slab: 32*128 floats = 1024 float4
        const float4* Wg = (const float4*)(W + ks * 128);
        float4* sW4 = (float4*)sW;
#pragma unroll
        for (int j = 0; j < 4; ++j) sW4[tid + 256 * j] = Wg[tid + 256 * j];
        // load X slab: 32 rows x 32 k
        {
            int xr = tid >> 3;            // 0..31
            int xc = (tid & 7) * 4;       // 0..28
            float4 xv = *(const float4*)(xin + (row0 + xr) * 128 + ks + xc);
            *(float4*)&sX[xr * 36 + xc] = xv;
        }
        __syncthreads();
#pragma unroll
        for (int kk = 0; kk < 32; ++kk) {
            float xa = sX[r0 * 36 + kk];
            float xb = sX[(r0 + 1) * 36 + kk];
            float4 w0 = *(float4*)&sW[kk * 128 + c0];
            float4 w1 = *(float4*)&sW[kk * 128 + c0 + 4];
            acc0[0] += xa * w0.x; acc0[1] += xa * w0.y; acc0[2] += xa * w0.z; acc0[3] += xa * w0.w;
            acc0[4] += xa * w1.x; acc0[5] += xa * w1.y; acc0[6] += xa * w1.z; acc0[7] += xa * w1.w;
            acc1[0] += xb * w0.x; acc1[1] += xb * w0.y; acc1[2] += xb * w0.z; acc1[3] += xb * w0.w;
            acc1[4] += xb * w1.x; acc1[5] += xb * w1.y; acc1[6] += xb * w1.z; acc1[7] += xb * w1.w;
        }
        __syncthreads();
    }

    const long gr0 = row0 + r0;
    const long gr1 = gr0 + 1;
    float d0 = dinv[gr0], d1 = dinv[gr1];

    float4 h0a = make_float4(acc0[0] * d0, acc0[1] * d0, acc0[2] * d0, acc0[3] * d0);
    float4 h0b = make_float4(acc0[4] * d0, acc0[5] * d0, acc0[6] * d0, acc0[7] * d0);
    float4 h1a = make_float4(acc1[0] * d1, acc1[1] * d1, acc1[2] * d1, acc1[3] * d1);
    float4 h1b = make_float4(acc1[4] * d1, acc1[5] * d1, acc1[6] * d1, acc1[7] * d1);

    *(float4*)(hs + gr0 * 128 + c0)     = h0a;
    *(float4*)(hs + gr0 * 128 + c0 + 4) = h0b;
    *(float4*)(hs + gr1 * 128 + c0)     = h1a;
    *(float4*)(hs + gr1 * 128 + c0 + 4) = h1b;

    float4 a0a = make_float4(h0a.x * d0, h0a.y * d0, h0a.z * d0, h0a.w * d0);
    float4 a0b = make_float4(h0b.x * d0, h0b.y * d0, h0b.z * d0, h0b.w * d0);
    float4 a1a = make_float4(h1a.x * d1, h1a.y * d1, h1a.z * d1, h1a.w * d1);
    float4 a1b = make_float4(h1b.x * d1, h1b.y * d1, h1b.z * d1, h1b.w * d1);

    *(float4*)(agg + gr0 * 128 + c0)     = a0a;
    *(float4*)(agg + gr0 * 128 + c0 + 4) = a0b;
    *(float4*)(agg + gr1 * 128 + c0)     = a1a;
    *(float4*)(agg + gr1 * 128 + c0 + 4) = a1b;
}

// ---------------- edge scatter: agg[d] += hs[s] * dinv[d] ----------------
// 32 threads per edge, float4 per thread.
__global__ void k_scatter(const int* __restrict__ src, const int* __restrict__ dst,
                          const float* __restrict__ dinv,
                          const float* __restrict__ hs, float* __restrict__ agg) {
    int t = blockIdx.x * 256 + threadIdx.x;
    int e = t >> 5;
    if (e >= NE) return;
    int lane = t & 31;
    int s = src[e], d = dst[e];
    float w = dinv[d];
    float4 hv = *(const float4*)(hs + (long)s * 128 + lane * 4);
    float* ap = agg + (long)d * 128 + lane * 4;
    atomAddF(ap + 0, hv.x * w);
    atomAddF(ap + 1, hv.y * w);
    atomAddF(ap + 2, hv.z * w);
    atomAddF(ap + 3, hv.w * w);
}

// ---------------- BN + ReLU in place ----------------
__global__ void k_bnrelu(float* __restrict__ x, const float* __restrict__ scale,
                         const float* __restrict__ shift) {
    int t = blockIdx.x * 256 + threadIdx.x;
    int i = t >> 5;
    if (i >= NN) return;
    int l = (t & 31) * 4;
    float4 v = *(float4*)(x + (long)i * 128 + l);
    float4 sc = *(const float4*)(scale + l);
    float4 sh = *(const float4*)(shift + l);
    v.x = fmaxf(v.x * sc.x + sh.x, 0.f);
    v.y = fmaxf(v.y * sc.y + sh.y, 0.f);
    v.z = fmaxf(v.z * sc.z + sh.z, 0.f);
    v.w = fmaxf(v.w * sc.w + sh.w, 0.f);
    *(float4*)(x + (long)i * 128 + l) = v;
}

// ---------------- pooling ----------------
__global__ void k_zero(float* p, int n) {
    int i = blockIdx.x * 256 + threadIdx.x;
    if (i < n) p[i] = 0.f;
}

__global__ void k_pool(const float* __restrict__ x, const int* __restrict__ batch,
                       float* __restrict__ pooled, float* __restrict__ cnt) {
    int t = blockIdx.x * 256 + threadIdx.x;
    int i = t >> 5;
    if (i >= NN) return;
    int lane = t & 31;
    int g = batch[i];
    float4 hv = *(const float4*)(x + (long)i * 128 + lane * 4);
    float* pp = pooled + (long)g * 128 + lane * 4;
    atomAddF(pp + 0, hv.x);
    atomAddF(pp + 1, hv.y);
    atomAddF(pp + 2, hv.z);
    atomAddF(pp + 3, hv.w);
    if (lane == 0) atomAddF(&cnt[g], 1.0f);
}

// out[g] = dot(pooled[g], Wl)/max(cnt,1) + bl  — one wave per graph
__global__ void k_final(const float* __restrict__ pooled, const float* __restrict__ cnt,
                        const float* __restrict__ Wl, const float* __restrict__ bl,
                        float* __restrict__ out) {
    int gw = (blockIdx.x * 256 + threadIdx.x) >> 6;
    if (gw >= NG) return;
    int lane = threadIdx.x & 63;
    const float* p = pooled + (long)gw * 128;
    float sum = p[lane] * Wl[lane] + p[lane + 64] * Wl[lane + 64];
#pragma unroll
    for (int o = 32; o > 0; o >>= 1) sum += __shfl_down(sum, o, 64);
    if (lane == 0) out[gw] = sum / fmaxf(cnt[gw], 1.0f) + bl[0];
}

// ---------------- launch ----------------
extern "C" void kernel_launch(void* const* d_in, const int* in_sizes, int n_in,
                              void* d_out, int out_size, void* d_ws, size_t ws_size,
                              hipStream_t stream) {
    const float* x   = (const float*)d_in[0];
    const int*   ei  = (const int*)d_in[1];
    const int*   bat = (const int*)d_in[2];
    const float* W1  = (const float*)d_in[3];
    const float* b1  = (const float*)d_in[4];
    const float* g1  = (const float*)d_in[5];
    const float* be1 = (const float*)d_in[6];
    const float* m1  = (const float*)d_in[7];
    const float* v1  = (const float*)d_in[8];
    const float* W2  = (const float*)d_in[9];
    const float* b2  = (const float*)d_in[10];
    const float* g2  = (const float*)d_in[11];
    const float* be2 = (const float*)d_in[12];
    const float* m2  = (const float*)d_in[13];
    const float* v2  = (const float*)d_in[14];
    const float* W3  = (const float*)d_in[15];
    const float* b3  = (const float*)d_in[16];
    const float* g3  = (const float*)d_in[17];
    const float* be3 = (const float*)d_in[18];
    const float* m3  = (const float*)d_in[19];
    const float* v3  = (const float*)d_in[20];
    const float* Wl  = (const float*)d_in[21];
    const float* bl  = (const float*)d_in[22];
    float* out = (float*)d_out;

    const int* srcp = ei;        // edge_index[0]
    const int* dstp = ei + NE;   // edge_index[1]

    // workspace layout (bytes)
    char* ws = (char*)d_ws;
    float* dinv   = (float*)(ws + 0);            // NN floats (400,000 B)
    float* scale1 = (float*)(ws + 400384);
    float* shift1 = (float*)(ws + 400384 + 512);
    float* scale2 = (float*)(ws + 400384 + 1024);
    float* shift2 = (float*)(ws + 400384 + 1536);
    float* scale3 = (float*)(ws + 400384 + 2048);
    float* shift3 = (float*)(ws + 400384 + 2560);
    float* pooled = (float*)(ws + 403456);       // NG*128 floats (262,144 B)
    float* cnt    = (float*)(ws + 665600);       // NG floats (2,048 B)
    float* hs     = (float*)(ws + 670720);       // NN*128 floats (51,200,000 B)
    float* agg    = (float*)(ws + 670720 + 51200000); // NN*128 floats

    // degree -> dinv
    k_deg_init<<<(NN + 255) / 256, 256, 0, stream>>>(dinv);
    k_deg_accum<<<(NE + 255) / 256, 256, 0, stream>>>(dstp, dinv);
    k_dinv<<<(NN + 255) / 256, 256, 0, stream>>>(dinv);

    // BN affine prep
    k_bn_prep<<<1, 128, 0, stream>>>(b1, g1, be1, m1, v1, scale1, shift1);
    k_bn_prep<<<1, 128, 0, stream>>>(b2, g2, be2, m2, v2, scale2, shift2);
    k_bn_prep<<<1, 128, 0, stream>>>(b3, g3, be3, m3, v3, scale3, shift3);

    const int gemm_grid = NN / GROWS;           // 3125, exact
    const int scat_grid = (NE * 32) / 256;      // 200000
    const int node_grid = (NN * 32 + 255) / 256;

    // layer 1: xin = x (input), output -> agg
    k_gemm<<<gemm_grid, 256, 0, stream>>>(x, W1, dinv, hs, agg);
    k_scatter<<<scat_grid, 256, 0, stream>>>(srcp, dstp, dinv, hs, agg);
    k_bnrelu<<<node_grid, 256, 0, stream>>>(agg, scale1, shift1);

    // layer 2: xin = agg (in-place safe: rows staged through LDS before write)
    k_gemm<<<gemm_grid, 256, 0, stream>>>(agg, W2, dinv, hs, agg);
    k_scatter<<<scat_grid, 256, 0, stream>>>(srcp, dstp, dinv, hs, agg);
    k_bnrelu<<<node_grid, 256, 0, stream>>>(agg, scale2, shift2);

    // layer 3
    k_gemm<<<gemm_grid, 256, 0, stream>>>(agg, W3, dinv, hs, agg);
    k_scatter<<<scat_grid, 256, 0, stream>>>(srcp, dstp, dinv, hs, agg);
    k_bnrelu<<<node_grid, 256, 0, stream>>>(agg, scale3, shift3);

    // pool + final linear
    k_zero<<<(NG * 128 + NG + 255) / 256, 256, 0, stream>>>(pooled, NG * 128 + NG);
    k_pool<<<node_grid, 256, 0, stream>>>(agg, bat, pooled, cnt);
    k_final<<<(NG * 64 + 255) / 256, 256, 0, stream>>>(pooled, cnt, Wl, bl, out);
}

// Round 2
// 888.341 us; speedup vs baseline: 9.9034x; 9.9034x over previous
//
#include <hip/hip_runtime.h>
#include <hip/hip_bf16.h>

// Problem constants (match reference)
#define NN 100000     // nodes
#define NE 1600000    // edges
#define HD 128        // feature/hidden dim
#define NG 512        // graphs
#define BN_EPS 1e-5f

__device__ __forceinline__ void atomAddF(float* p, float v) {
    unsafeAtomicAdd(p, v);
}

// ---------------- zero helpers ----------------
__global__ void k_zero_i(int* p, int n) {
    int i = blockIdx.x * 256 + threadIdx.x;
    if (i < n) p[i] = 0;
}

// ---------------- degree histogram (int atomics) ----------------
__global__ void k_hist(const int* __restrict__ dst, int* __restrict__ indeg) {
    int e = blockIdx.x * 256 + threadIdx.x;
    if (e < NE) atomicAdd(&indeg[dst[e]], 1);
}

// dinv = rsqrt(indeg + 1)  (self-loop included; always >= 1)
__global__ void k_dinv(const int* __restrict__ indeg, float* __restrict__ dinv) {
    int i = blockIdx.x * 256 + threadIdx.x;
    if (i < NN) dinv[i] = rsqrtf((float)(indeg[i] + 1));
}

// ---------------- hierarchical exclusive scan of indeg -> row_start ----------------
// scan1: 1024 elements per block (256 thr x 4), writes exclusive partials + block sums
__global__ void k_scan1(const int* __restrict__ indeg, int* __restrict__ rs, int* __restrict__ aux) {
    __shared__ int s[256];
    int t = threadIdx.x;
    int base = blockIdx.x * 1024 + t * 4;
    int v0 = 0, v1 = 0, v2 = 0, v3 = 0;
    if (base + 0 < NN) v0 = indeg[base + 0];
    if (base + 1 < NN) v1 = indeg[base + 1];
    if (base + 2 < NN) v2 = indeg[base + 2];
    if (base + 3 < NN) v3 = indeg[base + 3];
    int tsum = v0 + v1 + v2 + v3;
    s[t] = tsum;
    __syncthreads();
    for (int o = 1; o < 256; o <<= 1) {
        int x = 0;
        if (t >= o) x = s[t - o];
        __syncthreads();
        s[t] += x;
        __syncthreads();
    }
    int excl = s[t] - tsum;
    if (base + 0 < NN) rs[base + 0] = excl;
    if (base + 1 < NN) rs[base + 1] = excl + v0;
    if (base + 2 < NN) rs[base + 2] = excl + v0 + v1;
    if (base + 3 < NN) rs[base + 3] = excl + v0 + v1 + v2;
    if (t == 255) aux[blockIdx.x] = s[255];
}

// scan2: single block exclusive scan over block sums (<=128 blocks)
__global__ void k_scan2(int* __restrict__ aux, int nblk) {
    __shared__ int s[128];
    int t = threadIdx.x;
    int v = (t < nblk) ? aux[t] : 0;
    s[t] = v;
    __syncthreads();
    for (int o = 1; o < 128; o <<= 1) {
        int x = 0;
        if (t >= o) x = s[t - o];
        __syncthreads();
        s[t] += x;
        __syncthreads();
    }
    if (t < nblk) aux[t] = s[t] - v;
}

// scan3: add block offsets; set sentinel rs[NN] = NE
__global__ void k_scan3(int* __restrict__ rs, const int* __restrict__ aux) {
    int i = blockIdx.x * 256 + threadIdx.x;
    if (i < NN) rs[i] += aux[i >> 10];
    if (i == 0) rs[NN] = NE;
}

// ---------------- CSR fill: bucket src by dst ----------------
__global__ void k_fill(const int* __restrict__ src, const int* __restrict__ dst,
                       const int* __restrict__ rs, int* __restrict__ cursor,
                       int* __restrict__ csr) {
    int e = blockIdx.x * 256 + threadIdx.x;
    if (e >= NE) return;
    int d = dst[e];
    int pos = rs[d] + atomicAdd(&cursor[d], 1);
    csr[pos] = src[e];
}

// ---------------- BN affine prep ----------------
__global__ void k_bn_prep(const float* __restrict__ b, const float* __restrict__ g,
                          const float* __restrict__ be, const float* __restrict__ m,
                          const float* __restrict__ v, float* scale, float* shift) {
    int f = threadIdx.x;
    if (f < HD) {
        float sc = g[f] * rsqrtf(v[f] + BN_EPS);
        scale[f] = sc;
        shift[f] = (b[f] - m[f]) * sc + be[f];
    }
}

// ---------------- graph boundaries (batch is sorted) ----------------
__global__ void k_gstart(const int* __restrict__ batch, int* __restrict__ gstart) {
    int g = blockIdx.x * 256 + threadIdx.x;
    if (g > NG) return;
    if (g == NG) { gstart[NG] = NN; return; }
    int lo = 0, hi = NN;
    while (lo < hi) {
        int mid = (lo + hi) >> 1;
        if (batch[mid] < g) lo = mid + 1; else hi = mid;
    }
    gstart[g] = lo;
}

// ---------------- GEMM: hs = (x @ W) * dinv[row] ----------------
#define GROWS 32
__launch_bounds__(256)
__global__ void k_gemm(const float* __restrict__ xin, const float* __restrict__ W,
                       const float* __restrict__ dinv, float* __restrict__ hs) {
    __shared__ float sW[32 * 128];
    __shared__ float sX[32 * 36];
    const int tid = threadIdx.x;
    const long row0 = (long)blockIdx.x * GROWS;

    const int cg = tid & 15;
    const int rp = tid >> 4;
    const int c0 = cg * 8;
    const int r0 = rp * 2;

    float acc0[8], acc1[8];
#pragma unroll
    for (int j = 0; j < 8; ++j) { acc0[j] = 0.f; acc1[j] = 0.f; }

    for (int ks = 0; ks < 128; ks += 32) {
        const float4* Wg = (const float4*)(W + ks * 128);
        float4* sW4 = (float4*)sW;
#pragma unroll
        for (int j = 0; j < 4; ++j) sW4[tid + 256 * j] = Wg[tid + 256 * j];
        {
            int xr = tid >> 3;
            int xc = (tid & 7) * 4;
            float4 xv = *(const float4*)(xin + (row0 + xr) * 128 + ks + xc);
            *(float4*)&sX[xr * 36 + xc] = xv;
        }
        __syncthreads();
#pragma unroll
        for (int kk = 0; kk < 32; ++kk) {
            float xa = sX[r0 * 36 + kk];
            float xb = sX[(r0 + 1) * 36 + kk];
            float4 w0 = *(float4*)&sW[kk * 128 + c0];
            float4 w1 = *(float4*)&sW[kk * 128 + c0 + 4];
            acc0[0] += xa * w0.x; acc0[1] += xa * w0.y; acc0[2] += xa * w0.z; acc0[3] += xa * w0.w;
            acc0[4] += xa * w1.x; acc0[5] += xa * w1.y; acc0[6] += xa * w1.z; acc0[7] += xa * w1.w;
            acc1[0] += xb * w0.x; acc1[1] += xb * w0.y; acc1[2] += xb * w0.z; acc1[3] += xb * w0.w;
            acc1[4] += xb * w1.x; acc1[5] += xb * w1.y; acc1[6] += xb * w1.z; acc1[7] += xb * w1.w;
        }
        __syncthreads();
    }

    const long gr0 = row0 + r0;
    const long gr1 = gr0 + 1;
    float d0 = dinv[gr0], d1 = dinv[gr1];

    *(float4*)(hs + gr0 * 128 + c0)     = make_float4(acc0[0] * d0, acc0[1] * d0, acc0[2] * d0, acc0[3] * d0);
    *(float4*)(hs + gr0 * 128 + c0 + 4) = make_float4(acc0[4] * d0, acc0[5] * d0, acc0[6] * d0, acc0[7] * d0);
    *(float4*)(hs + gr1 * 128 + c0)     = make_float4(acc1[0] * d1, acc1[1] * d1, acc1[2] * d1, acc1[3] * d1);
    *(float4*)(hs + gr1 * 128 + c0 + 4) = make_float4(acc1[4] * d1, acc1[5] * d1, acc1[6] * d1, acc1[7] * d1);
}

// ---------------- gather + BN + ReLU fused ----------------
// xout[d] = relu( (dinv[d] * (hs[d] + sum_{s in in(d)} hs[s])) * scale + shift )
// 32 threads (half-wave) per node, float4 per lane.
__global__ void k_gather(const float* __restrict__ hs, const int* __restrict__ rs,
                         const int* __restrict__ csr, const float* __restrict__ dinv,
                         const float* __restrict__ scale, const float* __restrict__ shift,
                         float* __restrict__ xout) {
    int t = blockIdx.x * 256 + threadIdx.x;
    int d = t >> 5;
    if (d >= NN) return;
    int lane = t & 31;
    int l4 = lane * 4;
    int e0 = rs[d], e1 = rs[d + 1];

    float4 acc = *(const float4*)(hs + (long)d * 128 + l4);   // self-loop term
    int j = e0;
    for (; j + 1 < e1; j += 2) {
        int s0 = csr[j], s1 = csr[j + 1];
        float4 v0 = *(const float4*)(hs + (long)s0 * 128 + l4);
        float4 v1 = *(const float4*)(hs + (long)s1 * 128 + l4);
        acc.x += v0.x + v1.x; acc.y += v0.y + v1.y;
        acc.z += v0.z + v1.z; acc.w += v0.w + v1.w;
    }
    if (j < e1) {
        int s0 = csr[j];
        float4 v0 = *(const float4*)(hs + (long)s0 * 128 + l4);
        acc.x += v0.x; acc.y += v0.y; acc.z += v0.z; acc.w += v0.w;
    }

    float dd = dinv[d];
    float4 sc = *(const float4*)(scale + l4);
    float4 sh = *(const float4*)(shift + l4);
    float4 r;
    r.x = fmaxf(dd * acc.x * sc.x + sh.x, 0.f);
    r.y = fmaxf(dd * acc.y * sc.y + sh.y, 0.f);
    r.z = fmaxf(dd * acc.z * sc.z + sh.z, 0.f);
    r.w = fmaxf(dd * acc.w * sc.w + sh.w, 0.f);
    *(float4*)(xout + (long)d * 128 + l4) = r;
}

// ---------------- fused mean-pool + final linear ----------------
// one block (256 thr) per graph; rows [gstart[g], gstart[g+1]) are contiguous
__global__ void k_pool_final(const float* __restrict__ x, const int* __restrict__ gstart,
                             const float* __restrict__ Wl, const float* __restrict__ bl,
                             float* __restrict__ out) {
    __shared__ float red[256];
    int g = blockIdx.x;
    int tid = threadIdx.x;
    int f = tid & 127;
    int half = tid >> 7;
    int i0 = gstart[g], i1 = gstart[g + 1];

    float acc = 0.f;
    for (int i = i0 + half; i < i1; i += 2) acc += x[(long)i * 128 + f];
    red[tid] = acc;
    __syncthreads();
    if (tid < 128) red[tid] = (red[tid] + red[tid + 128]) * Wl[tid];
    __syncthreads();
    for (int o = 64; o > 0; o >>= 1) {
        if (tid < o) red[tid] += red[tid + o];
        __syncthreads();
    }
    if (tid == 0) out[g] = red[0] / fmaxf((float)(i1 - i0), 1.f) + bl[0];
}

// ---------------- launch ----------------
extern "C" void kernel_launch(void* const* d_in, const int* in_sizes, int n_in,
                              void* d_out, int out_size, void* d_ws, size_t ws_size,
                              hipStream_t stream) {
    const float* x   = (const float*)d_in[0];
    const int*   ei  = (const int*)d_in[1];
    const int*   bat = (const int*)d_in[2];
    const float* W1  = (const float*)d_in[3];
    const float* b1  = (const float*)d_in[4];
    const float* g1  = (const float*)d_in[5];
    const float* be1 = (const float*)d_in[6];
    const float* m1  = (const float*)d_in[7];
    const float* v1  = (const float*)d_in[8];
    const float* W2  = (const float*)d_in[9];
    const float* b2  = (const float*)d_in[10];
    const float* g2  = (const float*)d_in[11];
    const float* be2 = (const float*)d_in[12];
    const float* m2  = (const float*)d_in[13];
    const float* v2  = (const float*)d_in[14];
    const float* W3  = (const float*)d_in[15];
    const float* b3  = (const float*)d_in[16];
    const float* g3  = (const float*)d_in[17];
    const float* be3 = (const float*)d_in[18];
    const float* m3  = (const float*)d_in[19];
    const float* v3  = (const float*)d_in[20];
    const float* Wl  = (const float*)d_in[21];
    const float* bl  = (const float*)d_in[22];
    float* out = (float*)d_out;

    const int* srcp = ei;        // edge_index[0]
    const int* dstp = ei + NE;   // edge_index[1]

    // ---- workspace layout (bytes, 256-aligned blocks) ----
    char* ws = (char*)d_ws;
    size_t off = 0;
    auto alloc = [&](size_t bytes) { char* p = ws + off; off += (bytes + 255) & ~255ULL; return p; };
    float* dinv   = (float*)alloc(NN * 4);            // 400 KB
    int*   indeg  = (int*)  alloc(NN * 4);            // 400 KB (reused as cursor)
    int*   rs     = (int*)  alloc((NN + 1) * 4);      // 400 KB row_start
    int*   aux    = (int*)  alloc(128 * 4);
    int*   csr    = (int*)  alloc(NE * 4);            // 6.4 MB
    float* scale1 = (float*)alloc(HD * 4);
    float* shift1 = (float*)alloc(HD * 4);
    float* scale2 = (float*)alloc(HD * 4);
    float* shift2 = (float*)alloc(HD * 4);
    float* scale3 = (float*)alloc(HD * 4);
    float* shift3 = (float*)alloc(HD * 4);
    int*   gstart = (int*)  alloc((NG + 1) * 4);
    float* hs     = (float*)alloc((size_t)NN * HD * 4);   // 51.2 MB
    float* xbuf   = (float*)alloc((size_t)NN * HD * 4);   // 51.2 MB

    const int nblk_scan = (NN + 1023) / 1024;   // 98
    const int grid_n   = (NN + 255) / 256;      // node-wise
    const int grid_e   = (NE + 255) / 256;      // edge-wise
    const int gemm_grid = NN / GROWS;           // 3125, exact
    const int gath_grid = (NN * 32 + 255) / 256;

    // ---- CSR build ----
    k_zero_i<<<grid_n, 256, 0, stream>>>(indeg, NN);
    k_hist<<<grid_e, 256, 0, stream>>>(dstp, indeg);
    k_dinv<<<grid_n, 256, 0, stream>>>(indeg, dinv);
    k_scan1<<<nblk_scan, 256, 0, stream>>>(indeg, rs, aux);
    k_scan2<<<1, 128, 0, stream>>>(aux, nblk_scan);
    k_scan3<<<grid_n, 256, 0, stream>>>(rs, aux);
    k_zero_i<<<grid_n, 256, 0, stream>>>(indeg, NN);          // reuse as cursor
    k_fill<<<grid_e, 256, 0, stream>>>(srcp, dstp, rs, indeg, csr);

    // ---- BN prep + graph boundaries ----
    k_bn_prep<<<1, 128, 0, stream>>>(b1, g1, be1, m1, v1, scale1, shift1);
    k_bn_prep<<<1, 128, 0, stream>>>(b2, g2, be2, m2, v2, scale2, shift2);
    k_bn_prep<<<1, 128, 0, stream>>>(b3, g3, be3, m3, v3, scale3, shift3);
    k_gstart<<<3, 256, 0, stream>>>(bat, gstart);

    // ---- layer 1 ----
    k_gemm<<<gemm_grid, 256, 0, stream>>>(x, W1, dinv, hs);
    k_gather<<<gath_grid, 256, 0, stream>>>(hs, rs, csr, dinv, scale1, shift1, xbuf);
    // ---- layer 2 ----
    k_gemm<<<gemm_grid, 256, 0, stream>>>(xbuf, W2, dinv, hs);
    k_gather<<<gath_grid, 256, 0, stream>>>(hs, rs, csr, dinv, scale2, shift2, xbuf);
    // ---- layer 3 ----
    k_gemm<<<gemm_grid, 256, 0, stream>>>(xbuf, W3, dinv, hs);
    k_gather<<<gath_grid, 256, 0, stream>>>(hs, rs, csr, dinv, scale3, shift3, xbuf);

    // ---- pool + final ----
    k_pool_final<<<NG, 256, 0, stream>>>(xbuf, gstart, Wl, bl, out);
}

// Round 3
// 653.057 us; speedup vs baseline: 13.4714x; 1.3603x over previous
//
#include <hip/hip_runtime.h>
#include <hip/hip_bf16.h>

// Problem constants (match reference)
#define NN 100000     // nodes
#define NE 1600000    // edges
#define HD 128        // feature/hidden dim
#define NG 512        // graphs
#define BN_EPS 1e-5f

typedef __attribute__((ext_vector_type(8))) short short8;
typedef __attribute__((ext_vector_type(4))) float floatx4;

// ---- bf16 helpers (RNE) ----
__device__ __forceinline__ ushort f2bf(float f) {
    union { float f; uint u; } v; v.f = f;
    uint r = (v.u + 0x7FFF + ((v.u >> 16) & 1)) >> 16;
    return (ushort)r;
}
__device__ __forceinline__ float bflo(uint u) { union { uint u; float f; } v; v.u = u << 16; return v.f; }
__device__ __forceinline__ float bfhi(uint u) { union { uint u; float f; } v; v.u = u & 0xFFFF0000u; return v.f; }

// ---------------- zero helper ----------------
__global__ void k_zero_i(int* p, int n) {
    int i = blockIdx.x * 256 + threadIdx.x;
    if (i < n) p[i] = 0;
}

// ---------------- degree histogram ----------------
__global__ void k_hist(const int* __restrict__ dst, int* __restrict__ indeg) {
    int e = blockIdx.x * 256 + threadIdx.x;
    if (e < NE) atomicAdd(&indeg[dst[e]], 1);
}

__global__ void k_dinv(const int* __restrict__ indeg, float* __restrict__ dinv) {
    int i = blockIdx.x * 256 + threadIdx.x;
    if (i < NN) dinv[i] = rsqrtf((float)(indeg[i] + 1));
}

// ---------------- hierarchical exclusive scan ----------------
__global__ void k_scan1(const int* __restrict__ indeg, int* __restrict__ rs, int* __restrict__ aux) {
    __shared__ int s[256];
    int t = threadIdx.x;
    int base = blockIdx.x * 1024 + t * 4;
    int v0 = 0, v1 = 0, v2 = 0, v3 = 0;
    if (base + 0 < NN) v0 = indeg[base + 0];
    if (base + 1 < NN) v1 = indeg[base + 1];
    if (base + 2 < NN) v2 = indeg[base + 2];
    if (base + 3 < NN) v3 = indeg[base + 3];
    int tsum = v0 + v1 + v2 + v3;
    s[t] = tsum;
    __syncthreads();
    for (int o = 1; o < 256; o <<= 1) {
        int x = 0;
        if (t >= o) x = s[t - o];
        __syncthreads();
        s[t] += x;
        __syncthreads();
    }
    int excl = s[t] - tsum;
    if (base + 0 < NN) rs[base + 0] = excl;
    if (base + 1 < NN) rs[base + 1] = excl + v0;
    if (base + 2 < NN) rs[base + 2] = excl + v0 + v1;
    if (base + 3 < NN) rs[base + 3] = excl + v0 + v1 + v2;
    if (t == 255) aux[blockIdx.x] = s[255];
}

__global__ void k_scan2(int* __restrict__ aux, int nblk) {
    __shared__ int s[128];
    int t = threadIdx.x;
    int v = (t < nblk) ? aux[t] : 0;
    s[t] = v;
    __syncthreads();
    for (int o = 1; o < 128; o <<= 1) {
        int x = 0;
        if (t >= o) x = s[t - o];
        __syncthreads();
        s[t] += x;
        __syncthreads();
    }
    if (t < nblk) aux[t] = s[t] - v;
}

__global__ void k_scan3(int* __restrict__ rs, const int* __restrict__ aux) {
    int i = blockIdx.x * 256 + threadIdx.x;
    if (i < NN) rs[i] += aux[i >> 10];
    if (i == 0) rs[NN] = NE;
}

// ---------------- CSR fill ----------------
__global__ void k_fill(const int* __restrict__ src, const int* __restrict__ dst,
                       const int* __restrict__ rs, int* __restrict__ cursor,
                       int* __restrict__ csr) {
    int e = blockIdx.x * 256 + threadIdx.x;
    if (e >= NE) return;
    int d = dst[e];
    int pos = rs[d] + atomicAdd(&cursor[d], 1);
    csr[pos] = src[e];
}

// ---------------- BN affine prep ----------------
__global__ void k_bn_prep(const float* __restrict__ b, const float* __restrict__ g,
                          const float* __restrict__ be, const float* __restrict__ m,
                          const float* __restrict__ v, float* scale, float* shift) {
    int f = threadIdx.x;
    if (f < HD) {
        float sc = g[f] * rsqrtf(v[f] + BN_EPS);
        scale[f] = sc;
        shift[f] = (b[f] - m[f]) * sc + be[f];
    }
}

// ---------------- graph boundaries ----------------
__global__ void k_gstart(const int* __restrict__ batch, int* __restrict__ gstart) {
    int g = blockIdx.x * 256 + threadIdx.x;
    if (g > NG) return;
    if (g == NG) { gstart[NG] = NN; return; }
    int lo = 0, hi = NN;
    while (lo < hi) {
        int mid = (lo + hi) >> 1;
        if (batch[mid] < g) lo = mid + 1; else hi = mid;
    }
    gstart[g] = lo;
}

// ---------------- fp32 -> bf16 cast of input x ----------------
__global__ void k_cast(const float* __restrict__ x, ushort* __restrict__ xb) {
    long i = (long)(blockIdx.x * 256 + threadIdx.x) * 4;
    if (i >= (long)NN * 128) return;
    float4 v = *(const float4*)(x + i);
    uint2 o;
    o.x = (uint)f2bf(v.x) | ((uint)f2bf(v.y) << 16);
    o.y = (uint)f2bf(v.z) | ((uint)f2bf(v.w) << 16);
    *(uint2*)(xb + i) = o;
}

// ---------------- MFMA GEMM: hs = bf16( (xb @ W) * dinv[row] ) ----------------
// 256 thr = 4 waves; wave handles 16 rows x 128 cols, K=128 in 4 MFMA k-steps.
// W (fp32 row-major [k][n]) staged transposed+bf16 in LDS: sWt[n][k], stride 136.
#define WT_STRIDE 136
__launch_bounds__(256)
__global__ void k_gemm_mfma(const ushort* __restrict__ xb, const float* __restrict__ W,
                            const float* __restrict__ dinv, ushort* __restrict__ hs) {
    __shared__ ushort sWt[128 * WT_STRIDE];
    const int tid = threadIdx.x;
    for (int i = tid; i < 128 * 128; i += 256) {
        int k = i >> 7, n = i & 127;
        sWt[n * WT_STRIDE + k] = f2bf(W[i]);
    }
    __syncthreads();

    const int wave = tid >> 6, lane = tid & 63;
    const int m = lane & 15, kg = lane >> 4;      // col-in-tile / k-group
    const long row0 = (long)blockIdx.x * 64 + wave * 16;

    long arow = row0 + m;
    long arc = arow < NN ? arow : (NN - 1);
    short8 a[4];
#pragma unroll
    for (int s = 0; s < 4; ++s)
        a[s] = *(const short8*)(xb + arc * 128 + s * 32 + kg * 8);

    floatx4 acc[8];
#pragma unroll
    for (int ct = 0; ct < 8; ++ct) acc[ct] = (floatx4){0.f, 0.f, 0.f, 0.f};

#pragma unroll
    for (int s = 0; s < 4; ++s) {
#pragma unroll
        for (int ct = 0; ct < 8; ++ct) {
            short8 b = *(const short8*)&sWt[(ct * 16 + m) * WT_STRIDE + s * 32 + kg * 8];
            acc[ct] = __builtin_amdgcn_mfma_f32_16x16x32_bf16(a[s], b, acc[ct], 0, 0, 0);
        }
    }

#pragma unroll
    for (int r = 0; r < 4; ++r) {
        long orow = row0 + kg * 4 + r;
        if (orow < NN) {
            float dd = dinv[orow];
#pragma unroll
            for (int ct = 0; ct < 8; ++ct)
                hs[orow * 128 + ct * 16 + m] = f2bf(acc[ct][r] * dd);
        }
    }
}

// ---------------- gather + BN + ReLU fused (bf16 rows, fp32 accumulate) ----------------
__global__ void k_gather_bf(const ushort* __restrict__ hs, const int* __restrict__ rs,
                            const int* __restrict__ csr, const float* __restrict__ dinv,
                            const float* __restrict__ scale, const float* __restrict__ shift,
                            ushort* __restrict__ xout) {
    int t = blockIdx.x * 256 + threadIdx.x;
    int d = t >> 5;
    if (d >= NN) return;
    int lane = t & 31;
    int c0 = lane * 4;
    int e0 = rs[d], e1 = rs[d + 1];

    uint2 sv = *(const uint2*)(hs + (long)d * 128 + c0);   // self-loop term
    float a0 = bflo(sv.x), a1 = bfhi(sv.x), a2 = bflo(sv.y), a3 = bfhi(sv.y);

    int j = e0;
    for (; j + 1 < e1; j += 2) {
        int s0 = csr[j], s1 = csr[j + 1];
        uint2 v0 = *(const uint2*)(hs + (long)s0 * 128 + c0);
        uint2 v1 = *(const uint2*)(hs + (long)s1 * 128 + c0);
        a0 += bflo(v0.x) + bflo(v1.x);
        a1 += bfhi(v0.x) + bfhi(v1.x);
        a2 += bflo(v0.y) + bflo(v1.y);
        a3 += bfhi(v0.y) + bfhi(v1.y);
    }
    if (j < e1) {
        int s0 = csr[j];
        uint2 v0 = *(const uint2*)(hs + (long)s0 * 128 + c0);
        a0 += bflo(v0.x); a1 += bfhi(v0.x); a2 += bflo(v0.y); a3 += bfhi(v0.y);
    }

    float dd = dinv[d];
    float4 sc = *(const float4*)(scale + c0);
    float4 sh = *(const float4*)(shift + c0);
    float r0 = fmaxf(dd * a0 * sc.x + sh.x, 0.f);
    float r1 = fmaxf(dd * a1 * sc.y + sh.y, 0.f);
    float r2 = fmaxf(dd * a2 * sc.z + sh.z, 0.f);
    float r3 = fmaxf(dd * a3 * sc.w + sh.w, 0.f);
    uint2 o;
    o.x = (uint)f2bf(r0) | ((uint)f2bf(r1) << 16);
    o.y = (uint)f2bf(r2) | ((uint)f2bf(r3) << 16);
    *(uint2*)(xout + (long)d * 128 + c0) = o;
}

// ---------------- fused mean-pool + final linear (bf16 input) ----------------
__global__ void k_pool_final(const ushort* __restrict__ x, const int* __restrict__ gstart,
                             const float* __restrict__ Wl, const float* __restrict__ bl,
                             float* __restrict__ out) {
    __shared__ float red[256];
    int g = blockIdx.x;
    int tid = threadIdx.x;
    int f = tid & 127;
    int half = tid >> 7;
    int i0 = gstart[g], i1 = gstart[g + 1];

    float acc = 0.f;
    for (int i = i0 + half; i < i1; i += 2) {
        ushort u = x[(long)i * 128 + f];
        acc += bflo((uint)u | 0xFFFF0000u ? (uint)u : 0u) * 0.f + 0.f, acc += 0.f; // (placeholder removed below)
    }
    // NOTE: loop above replaced — see k_pool_final_impl
    red[tid] = acc;
    __syncthreads();
    if (tid < 128) red[tid] = (red[tid] + red[tid + 128]) * Wl[tid];
    __syncthreads();
    for (int o = 64; o > 0; o >>= 1) {
        if (tid < o) red[tid] += red[tid + o];
        __syncthreads();
    }
    if (tid == 0) out[g] = red[0] / fmaxf((float)(i1 - i0), 1.f) + bl[0];
}

// clean implementation (the one actually launched)
__global__ void k_pool_final2(const ushort* __restrict__ x, const int* __restrict__ gstart,
                              const float* __restrict__ Wl, const float* __restrict__ bl,
                              float* __restrict__ out) {
    __shared__ float red[256];
    int g = blockIdx.x;
    int tid = threadIdx.x;
    int f = tid & 127;
    int half = tid >> 7;
    int i0 = gstart[g], i1 = gstart[g + 1];

    float acc = 0.f;
    for (int i = i0 + half; i < i1; i += 2) {
        uint u = (uint)x[(long)i * 128 + f] << 16;
        union { uint u; float f; } v; v.u = u;
        acc += v.f;
    }
    red[tid] = acc;
    __syncthreads();
    if (tid < 128) red[tid] = (red[tid] + red[tid + 128]) * Wl[tid];
    __syncthreads();
    for (int o = 64; o > 0; o >>= 1) {
        if (tid < o) red[tid] += red[tid + o];
        __syncthreads();
    }
    if (tid == 0) out[g] = red[0] / fmaxf((float)(i1 - i0), 1.f) + bl[0];
}

// ---------------- launch ----------------
extern "C" void kernel_launch(void* const* d_in, const int* in_sizes, int n_in,
                              void* d_out, int out_size, void* d_ws, size_t ws_size,
                              hipStream_t stream) {
    const float* x   = (const float*)d_in[0];
    const int*   ei  = (const int*)d_in[1];
    const int*   bat = (const int*)d_in[2];
    const float* W1  = (const float*)d_in[3];
    const float* b1  = (const float*)d_in[4];
    const float* g1  = (const float*)d_in[5];
    const float* be1 = (const float*)d_in[6];
    const float* m1  = (const float*)d_in[7];
    const float* v1  = (const float*)d_in[8];
    const float* W2  = (const float*)d_in[9];
    const float* b2  = (const float*)d_in[10];
    const float* g2  = (const float*)d_in[11];
    const float* be2 = (const float*)d_in[12];
    const float* m2  = (const float*)d_in[13];
    const float* v2  = (const float*)d_in[14];
    const float* W3  = (const float*)d_in[15];
    const float* b3  = (const float*)d_in[16];
    const float* g3  = (const float*)d_in[17];
    const float* be3 = (const float*)d_in[18];
    const float* m3  = (const float*)d_in[19];
    const float* v3  = (const float*)d_in[20];
    const float* Wl  = (const float*)d_in[21];
    const float* bl  = (const float*)d_in[22];
    float* out = (float*)d_out;

    const int* srcp = ei;        // edge_index[0]
    const int* dstp = ei + NE;   // edge_index[1]

    // ---- workspace layout ----
    char* ws = (char*)d_ws;
    size_t off = 0;
    auto alloc = [&](size_t bytes) { char* p = ws + off; off += (bytes + 255) & ~255ULL; return p; };
    float*  dinv   = (float*) alloc(NN * 4);
    int*    indeg  = (int*)   alloc(NN * 4);           // reused as cursor
    int*    rs     = (int*)   alloc((NN + 1) * 4);
    int*    aux    = (int*)   alloc(128 * 4);
    int*    csr    = (int*)   alloc(NE * 4);           // 6.4 MB
    float*  scale1 = (float*) alloc(HD * 4);
    float*  shift1 = (float*) alloc(HD * 4);
    float*  scale2 = (float*) alloc(HD * 4);
    float*  shift2 = (float*) alloc(HD * 4);
    float*  scale3 = (float*) alloc(HD * 4);
    float*  shift3 = (float*) alloc(HD * 4);
    int*    gstart = (int*)   alloc((NG + 1) * 4);
    ushort* xb     = (ushort*)alloc((size_t)NN * HD * 2);   // 25.6 MB bf16 input
    ushort* hs     = (ushort*)alloc((size_t)NN * HD * 2);   // 25.6 MB
    ushort* xbuf   = (ushort*)alloc((size_t)NN * HD * 2);   // 25.6 MB

    const int nblk_scan = (NN + 1023) / 1024;
    const int grid_n    = (NN + 255) / 256;
    const int grid_e    = (NE + 255) / 256;
    const int gemm_grid = (NN + 63) / 64;                   // 1563
    const int gath_grid = (NN * 32 + 255) / 256;
    const int cast_grid = (NN * 128 / 4 + 255) / 256;       // 12500

    // ---- CSR build ----
    k_zero_i<<<grid_n, 256, 0, stream>>>(indeg, NN);
    k_hist<<<grid_e, 256, 0, stream>>>(dstp, indeg);
    k_dinv<<<grid_n, 256, 0, stream>>>(indeg, dinv);
    k_scan1<<<nblk_scan, 256, 0, stream>>>(indeg, rs, aux);
    k_scan2<<<1, 128, 0, stream>>>(aux, nblk_scan);
    k_scan3<<<grid_n, 256, 0, stream>>>(rs, aux);
    k_zero_i<<<grid_n, 256, 0, stream>>>(indeg, NN);
    k_fill<<<grid_e, 256, 0, stream>>>(srcp, dstp, rs, indeg, csr);

    // ---- BN prep + graph boundaries + input cast ----
    k_bn_prep<<<1, 128, 0, stream>>>(b1, g1, be1, m1, v1, scale1, shift1);
    k_bn_prep<<<1, 128, 0, stream>>>(b2, g2, be2, m2, v2, scale2, shift2);
    k_bn_prep<<<1, 128, 0, stream>>>(b3, g3, be3, m3, v3, scale3, shift3);
    k_gstart<<<3, 256, 0, stream>>>(bat, gstart);
    k_cast<<<cast_grid, 256, 0, stream>>>(x, xb);

    // ---- layer 1 ----
    k_gemm_mfma<<<gemm_grid, 256, 0, stream>>>(xb, W1, dinv, hs);
    k_gather_bf<<<gath_grid, 256, 0, stream>>>(hs, rs, csr, dinv, scale1, shift1, xbuf);
    // ---- layer 2 ----
    k_gemm_mfma<<<gemm_grid, 256, 0, stream>>>(xbuf, W2, dinv, hs);
    k_gather_bf<<<gath_grid, 256, 0, stream>>>(hs, rs, csr, dinv, scale2, shift2, xbuf);
    // ---- layer 3 ----
    k_gemm_mfma<<<gemm_grid, 256, 0, stream>>>(xbuf, W3, dinv, hs);
    k_gather_bf<<<gath_grid, 256, 0, stream>>>(hs, rs, csr, dinv, scale3, shift3, xbuf);

    // ---- pool + final ----
    k_pool_final2<<<NG, 256, 0, stream>>>(xbuf, gstart, Wl, bl, out);
}

// Round 4
// 524.849 us; speedup vs baseline: 16.7621x; 1.2443x over previous
//
#include <hip/hip_runtime.h>
#include <hip/hip_bf16.h>

// Problem constants (match reference)
#define NN 100000     // nodes
#define NE 1600000    // edges
#define HD 128        // feature/hidden dim
#define NG 512        // graphs
#define BN_EPS 1e-5f

typedef __attribute__((ext_vector_type(8))) short short8;
typedef __attribute__((ext_vector_type(4))) float floatx4;

// ---- bf16 helpers (RNE) ----
__device__ __forceinline__ ushort f2bf(float f) {
    union { float f; uint u; } v; v.f = f;
    uint r = (v.u + 0x7FFF + ((v.u >> 16) & 1)) >> 16;
    return (ushort)r;
}
__device__ __forceinline__ float bflo(uint u) { union { uint u; float f; } v; v.u = u << 16; return v.f; }
__device__ __forceinline__ float bfhi(uint u) { union { uint u; float f; } v; v.u = u & 0xFFFF0000u; return v.f; }

// ---------------- zero helper ----------------
__global__ void k_zero_i(int* p, int n) {
    int i = blockIdx.x * 256 + threadIdx.x;
    if (i < n) p[i] = 0;
}

// ---------------- degree histogram + per-edge rank (ONE atomic pass) ----------------
__global__ void k_hist_rank(const int* __restrict__ dst, int* __restrict__ indeg,
                            int* __restrict__ rank) {
    int e = blockIdx.x * 256 + threadIdx.x;
    if (e < NE) rank[e] = atomicAdd(&indeg[dst[e]], 1);
}

__global__ void k_dinv(const int* __restrict__ indeg, float* __restrict__ dinv) {
    int i = blockIdx.x * 256 + threadIdx.x;
    if (i < NN) dinv[i] = rsqrtf((float)(indeg[i] + 1));
}

// ---------------- hierarchical exclusive scan ----------------
__global__ void k_scan1(const int* __restrict__ indeg, int* __restrict__ rs, int* __restrict__ aux) {
    __shared__ int s[256];
    int t = threadIdx.x;
    int base = blockIdx.x * 1024 + t * 4;
    int v0 = 0, v1 = 0, v2 = 0, v3 = 0;
    if (base + 0 < NN) v0 = indeg[base + 0];
    if (base + 1 < NN) v1 = indeg[base + 1];
    if (base + 2 < NN) v2 = indeg[base + 2];
    if (base + 3 < NN) v3 = indeg[base + 3];
    int tsum = v0 + v1 + v2 + v3;
    s[t] = tsum;
    __syncthreads();
    for (int o = 1; o < 256; o <<= 1) {
        int x = 0;
        if (t >= o) x = s[t - o];
        __syncthreads();
        s[t] += x;
        __syncthreads();
    }
    int excl = s[t] - tsum;
    if (base + 0 < NN) rs[base + 0] = excl;
    if (base + 1 < NN) rs[base + 1] = excl + v0;
    if (base + 2 < NN) rs[base + 2] = excl + v0 + v1;
    if (base + 3 < NN) rs[base + 3] = excl + v0 + v1 + v2;
    if (t == 255) aux[blockIdx.x] = s[255];
}

__global__ void k_scan2(int* __restrict__ aux, int nblk) {
    __shared__ int s[128];
    int t = threadIdx.x;
    int v = (t < nblk) ? aux[t] : 0;
    s[t] = v;
    __syncthreads();
    for (int o = 1; o < 128; o <<= 1) {
        int x = 0;
        if (t >= o) x = s[t - o];
        __syncthreads();
        s[t] += x;
        __syncthreads();
    }
    if (t < nblk) aux[t] = s[t] - v;
}

__global__ void k_scan3(int* __restrict__ rs, const int* __restrict__ aux) {
    int i = blockIdx.x * 256 + threadIdx.x;
    if (i < NN) rs[i] += aux[i >> 10];
    if (i == 0) rs[NN] = NE;
}

// ---------------- CSR fill (atomic-free) ----------------
__global__ void k_fill(const int* __restrict__ src, const int* __restrict__ dst,
                       const int* __restrict__ rank, const int* __restrict__ rs,
                       int* __restrict__ csr) {
    int e = blockIdx.x * 256 + threadIdx.x;
    if (e >= NE) return;
    csr[rs[dst[e]] + rank[e]] = src[e];
}

// ---------------- BN affine prep ----------------
__global__ void k_bn_prep(const float* __restrict__ b, const float* __restrict__ g,
                          const float* __restrict__ be, const float* __restrict__ m,
                          const float* __restrict__ v, float* scale, float* shift) {
    int f = threadIdx.x;
    if (f < HD) {
        float sc = g[f] * rsqrtf(v[f] + BN_EPS);
        scale[f] = sc;
        shift[f] = (b[f] - m[f]) * sc + be[f];
    }
}

// ---------------- graph boundaries ----------------
__global__ void k_gstart(const int* __restrict__ batch, int* __restrict__ gstart) {
    int g = blockIdx.x * 256 + threadIdx.x;
    if (g > NG) return;
    if (g == NG) { gstart[NG] = NN; return; }
    int lo = 0, hi = NN;
    while (lo < hi) {
        int mid = (lo + hi) >> 1;
        if (batch[mid] < g) lo = mid + 1; else hi = mid;
    }
    gstart[g] = lo;
}

// ---------------- fp32 -> bf16 cast of input x ----------------
__global__ void k_cast(const float* __restrict__ x, ushort* __restrict__ xb) {
    long i = (long)(blockIdx.x * 256 + threadIdx.x) * 4;
    if (i >= (long)NN * 128) return;
    float4 v = *(const float4*)(x + i);
    uint2 o;
    o.x = (uint)f2bf(v.x) | ((uint)f2bf(v.y) << 16);
    o.y = (uint)f2bf(v.z) | ((uint)f2bf(v.w) << 16);
    *(uint2*)(xb + i) = o;
}

// ---------------- MFMA GEMM: hs = bf16( (xb @ W) * dinv[row] ) ----------------
#define WT_STRIDE 136
__launch_bounds__(256)
__global__ void k_gemm_mfma(const ushort* __restrict__ xb, const float* __restrict__ W,
                            const float* __restrict__ dinv, ushort* __restrict__ hs) {
    __shared__ ushort sWt[128 * WT_STRIDE];
    const int tid = threadIdx.x;
    for (int i = tid; i < 128 * 128; i += 256) {
        int k = i >> 7, n = i & 127;
        sWt[n * WT_STRIDE + k] = f2bf(W[i]);
    }
    __syncthreads();

    const int wave = tid >> 6, lane = tid & 63;
    const int m = lane & 15, kg = lane >> 4;
    const long row0 = (long)blockIdx.x * 64 + wave * 16;

    long arow = row0 + m;
    long arc = arow < NN ? arow : (NN - 1);
    short8 a[4];
#pragma unroll
    for (int s = 0; s < 4; ++s)
        a[s] = *(const short8*)(xb + arc * 128 + s * 32 + kg * 8);

    floatx4 acc[8];
#pragma unroll
    for (int ct = 0; ct < 8; ++ct) acc[ct] = (floatx4){0.f, 0.f, 0.f, 0.f};

#pragma unroll
    for (int s = 0; s < 4; ++s) {
#pragma unroll
        for (int ct = 0; ct < 8; ++ct) {
            short8 b = *(const short8*)&sWt[(ct * 16 + m) * WT_STRIDE + s * 32 + kg * 8];
            acc[ct] = __builtin_amdgcn_mfma_f32_16x16x32_bf16(a[s], b, acc[ct], 0, 0, 0);
        }
    }

#pragma unroll
    for (int r = 0; r < 4; ++r) {
        long orow = row0 + kg * 4 + r;
        if (orow < NN) {
            float dd = dinv[orow];
#pragma unroll
            for (int ct = 0; ct < 8; ++ct)
                hs[orow * 128 + ct * 16 + m] = f2bf(acc[ct][r] * dd);
        }
    }
}

// ---------------- gather + BN + ReLU fused: 16 lanes/node, uint4 (16B) loads ----------------
__global__ void k_gather_bf(const ushort* __restrict__ hs, const int* __restrict__ rs,
                            const int* __restrict__ csr, const float* __restrict__ dinv,
                            const float* __restrict__ scale, const float* __restrict__ shift,
                            ushort* __restrict__ xout) {
    int t = blockIdx.x * 256 + threadIdx.x;
    int d = t >> 4;
    if (d >= NN) return;
    int lane = t & 15;
    int c0 = lane * 8;
    int e0 = rs[d], e1 = rs[d + 1];

    uint4 sv = *(const uint4*)(hs + (long)d * 128 + c0);   // self-loop term
    float a0 = bflo(sv.x), a1 = bfhi(sv.x), a2 = bflo(sv.y), a3 = bfhi(sv.y);
    float a4 = bflo(sv.z), a5 = bfhi(sv.z), a6 = bflo(sv.w), a7 = bfhi(sv.w);

    int j = e0;
    for (; j + 1 < e1; j += 2) {
        int s0 = csr[j], s1 = csr[j + 1];
        uint4 v0 = *(const uint4*)(hs + (long)s0 * 128 + c0);
        uint4 v1 = *(const uint4*)(hs + (long)s1 * 128 + c0);
        a0 += bflo(v0.x) + bflo(v1.x); a1 += bfhi(v0.x) + bfhi(v1.x);
        a2 += bflo(v0.y) + bflo(v1.y); a3 += bfhi(v0.y) + bfhi(v1.y);
        a4 += bflo(v0.z) + bflo(v1.z); a5 += bfhi(v0.z) + bfhi(v1.z);
        a6 += bflo(v0.w) + bflo(v1.w); a7 += bfhi(v0.w) + bfhi(v1.w);
    }
    if (j < e1) {
        int s0 = csr[j];
        uint4 v0 = *(const uint4*)(hs + (long)s0 * 128 + c0);
        a0 += bflo(v0.x); a1 += bfhi(v0.x);
        a2 += bflo(v0.y); a3 += bfhi(v0.y);
        a4 += bflo(v0.z); a5 += bfhi(v0.z);
        a6 += bflo(v0.w); a7 += bfhi(v0.w);
    }

    float dd = dinv[d];
    float4 sca = *(const float4*)(scale + c0);
    float4 scb = *(const float4*)(scale + c0 + 4);
    float4 sha = *(const float4*)(shift + c0);
    float4 shb = *(const float4*)(shift + c0 + 4);
    float r0 = fmaxf(dd * a0 * sca.x + sha.x, 0.f);
    float r1 = fmaxf(dd * a1 * sca.y + sha.y, 0.f);
    float r2 = fmaxf(dd * a2 * sca.z + sha.z, 0.f);
    float r3 = fmaxf(dd * a3 * sca.w + sha.w, 0.f);
    float r4 = fmaxf(dd * a4 * scb.x + shb.x, 0.f);
    float r5 = fmaxf(dd * a5 * scb.y + shb.y, 0.f);
    float r6 = fmaxf(dd * a6 * scb.z + shb.z, 0.f);
    float r7 = fmaxf(dd * a7 * scb.w + shb.w, 0.f);
    uint4 o;
    o.x = (uint)f2bf(r0) | ((uint)f2bf(r1) << 16);
    o.y = (uint)f2bf(r2) | ((uint)f2bf(r3) << 16);
    o.z = (uint)f2bf(r4) | ((uint)f2bf(r5) << 16);
    o.w = (uint)f2bf(r6) | ((uint)f2bf(r7) << 16);
    *(uint4*)(xout + (long)d * 128 + c0) = o;
}

// ---------------- fused mean-pool + final linear (bf16 input) ----------------
__global__ void k_pool_final2(const ushort* __restrict__ x, const int* __restrict__ gstart,
                              const float* __restrict__ Wl, const float* __restrict__ bl,
                              float* __restrict__ out) {
    __shared__ float red[256];
    int g = blockIdx.x;
    int tid = threadIdx.x;
    int f = tid & 127;
    int half = tid >> 7;
    int i0 = gstart[g], i1 = gstart[g + 1];

    float acc = 0.f;
    for (int i = i0 + half; i < i1; i += 2) {
        union { uint u; float f; } v; v.u = (uint)x[(long)i * 128 + f] << 16;
        acc += v.f;
    }
    red[tid] = acc;
    __syncthreads();
    if (tid < 128) red[tid] = (red[tid] + red[tid + 128]) * Wl[tid];
    __syncthreads();
    for (int o = 64; o > 0; o >>= 1) {
        if (tid < o) red[tid] += red[tid + o];
        __syncthreads();
    }
    if (tid == 0) out[g] = red[0] / fmaxf((float)(i1 - i0), 1.f) + bl[0];
}

// ---------------- launch ----------------
extern "C" void kernel_launch(void* const* d_in, const int* in_sizes, int n_in,
                              void* d_out, int out_size, void* d_ws, size_t ws_size,
                              hipStream_t stream) {
    const float* x   = (const float*)d_in[0];
    const int*   ei  = (const int*)d_in[1];
    const int*   bat = (const int*)d_in[2];
    const float* W1  = (const float*)d_in[3];
    const float* b1  = (const float*)d_in[4];
    const float* g1  = (const float*)d_in[5];
    const float* be1 = (const float*)d_in[6];
    const float* m1  = (const float*)d_in[7];
    const float* v1  = (const float*)d_in[8];
    const float* W2  = (const float*)d_in[9];
    const float* b2  = (const float*)d_in[10];
    const float* g2  = (const float*)d_in[11];
    const float* be2 = (const float*)d_in[12];
    const float* m2  = (const float*)d_in[13];
    const float* v2  = (const float*)d_in[14];
    const float* W3  = (const float*)d_in[15];
    const float* b3  = (const float*)d_in[16];
    const float* g3  = (const float*)d_in[17];
    const float* be3 = (const float*)d_in[18];
    const float* m3  = (const float*)d_in[19];
    const float* v3  = (const float*)d_in[20];
    const float* Wl  = (const float*)d_in[21];
    const float* bl  = (const float*)d_in[22];
    float* out = (float*)d_out;

    const int* srcp = ei;        // edge_index[0]
    const int* dstp = ei + NE;   // edge_index[1]

    // ---- workspace layout ----
    char* ws = (char*)d_ws;
    size_t off = 0;
    auto alloc = [&](size_t bytes) { char* p = ws + off; off += (bytes + 255) & ~255ULL; return p; };
    float*  dinv   = (float*) alloc(NN * 4);
    int*    indeg  = (int*)   alloc(NN * 4);
    int*    rs     = (int*)   alloc((NN + 1) * 4);
    int*    aux    = (int*)   alloc(128 * 4);
    int*    csr    = (int*)   alloc(NE * 4);           // 6.4 MB
    int*    rank   = (int*)   alloc(NE * 4);           // 6.4 MB
    float*  scale1 = (float*) alloc(HD * 4);
    float*  shift1 = (float*) alloc(HD * 4);
    float*  scale2 = (float*) alloc(HD * 4);
    float*  shift2 = (float*) alloc(HD * 4);
    float*  scale3 = (float*) alloc(HD * 4);
    float*  shift3 = (float*) alloc(HD * 4);
    int*    gstart = (int*)   alloc((NG + 1) * 4);
    ushort* xb     = (ushort*)alloc((size_t)NN * HD * 2);   // 25.6 MB
    ushort* hs     = (ushort*)alloc((size_t)NN * HD * 2);   // 25.6 MB
    ushort* xbuf   = (ushort*)alloc((size_t)NN * HD * 2);   // 25.6 MB

    const int nblk_scan = (NN + 1023) / 1024;
    const int grid_n    = (NN + 255) / 256;
    const int grid_e    = (NE + 255) / 256;
    const int gemm_grid = (NN + 63) / 64;                   // 1563
    const int gath_grid = (NN * 16 + 255) / 256;            // 6250
    const int cast_grid = (NN * 128 / 4 + 255) / 256;

    // ---- CSR build: one atomic pass (hist+rank), then atomic-free fill ----
    k_zero_i<<<grid_n, 256, 0, stream>>>(indeg, NN);
    k_hist_rank<<<grid_e, 256, 0, stream>>>(dstp, indeg, rank);
    k_dinv<<<grid_n, 256, 0, stream>>>(indeg, dinv);
    k_scan1<<<nblk_scan, 256, 0, stream>>>(indeg, rs, aux);
    k_scan2<<<1, 128, 0, stream>>>(aux, nblk_scan);
    k_scan3<<<grid_n, 256, 0, stream>>>(rs, aux);
    k_fill<<<grid_e, 256, 0, stream>>>(srcp, dstp, rank, rs, csr);

    // ---- BN prep + graph boundaries + input cast ----
    k_bn_prep<<<1, 128, 0, stream>>>(b1, g1, be1, m1, v1, scale1, shift1);
    k_bn_prep<<<1, 128, 0, stream>>>(b2, g2, be2, m2, v2, scale2, shift2);
    k_bn_prep<<<1, 128, 0, stream>>>(b3, g3, be3, m3, v3, scale3, shift3);
    k_gstart<<<3, 256, 0, stream>>>(bat, gstart);
    k_cast<<<cast_grid, 256, 0, stream>>>(x, xb);

    // ---- layer 1 ----
    k_gemm_mfma<<<gemm_grid, 256, 0, stream>>>(xb, W1, dinv, hs);
    k_gather_bf<<<gath_grid, 256, 0, stream>>>(hs, rs, csr, dinv, scale1, shift1, xbuf);
    // ---- layer 2 ----
    k_gemm_mfma<<<gemm_grid, 256, 0, stream>>>(xbuf, W2, dinv, hs);
    k_gather_bf<<<gath_grid, 256, 0, stream>>>(hs, rs, csr, dinv, scale2, shift2, xbuf);
    // ---- layer 3 ----
    k_gemm_mfma<<<gemm_grid, 256, 0, stream>>>(xbuf, W3, dinv, hs);
    k_gather_bf<<<gath_grid, 256, 0, stream>>>(hs, rs, csr, dinv, scale3, shift3, xbuf);

    // ---- pool + final ----
    k_pool_final2<<<NG, 256, 0, stream>>>(xbuf, gstart, Wl, bl, out);
}